// Round 2
// baseline (199.165 us; speedup 1.0000x reference)
//
#include <hip/hip_runtime.h>
#include <hip/hip_bf16.h>
#include <stdint.h>

typedef float v4f __attribute__((ext_vector_type(4)));
typedef short v8s __attribute__((ext_vector_type(8)));

#define LOG2E 1.44269504088896f
#define QSCALE (0.125f * LOG2E)   // fold softmax log2-domain into Q pre-scale
#define SOFTMAX_OFF 16.0f         // fixed softmax offset (exact; cancels in O/l)

__device__ __forceinline__ unsigned short f2bf(float f) {
    unsigned int u = __float_as_uint(f);
    u += 0x7fffu + ((u >> 16) & 1u);          // RTNE
    return (unsigned short)(u >> 16);
}

// Compiler+HW LDS ordering fence for the intra-wave P exchange.
#define LDS_FENCE() __builtin_amdgcn_fence(__ATOMIC_ACQ_REL, "workgroup")

// async global->LDS, 16B per lane, LDS dest = wave-uniform base + lane*16
__device__ __forceinline__ void gload_lds16(const unsigned short* g, unsigned short* s) {
    __builtin_amdgcn_global_load_lds(
        (const __attribute__((address_space(1))) unsigned int*)g,
        (__attribute__((address_space(3))) unsigned int*)s, 16, 0, 0);
}

// barriers with memory clobber: loads may not be hoisted/sunk across
#define BAR()      asm volatile("s_barrier" ::: "memory")
#define VMWAIT(N)  asm volatile("s_waitcnt vmcnt(" #N ")" ::: "memory")

#define PIPE_BARRIER_KEEP4()                                   \
    do {                                                       \
        asm volatile("s_waitcnt vmcnt(4)" ::: "memory");       \
        __builtin_amdgcn_s_barrier();                          \
        asm volatile("" ::: "memory");                         \
    } while (0)
#define PIPE_BARRIER_DRAIN()                                   \
    do {                                                       \
        asm volatile("s_waitcnt vmcnt(0)" ::: "memory");       \
        __builtin_amdgcn_s_barrier();                          \
        asm volatile("" ::: "memory");                         \
    } while (0)

// ---------------- prep: cast + rope table + both weight transposes ----------------
__global__ void k_prep(const float* __restrict__ x,
                       const float* __restrict__ w_qkv,
                       const float* __restrict__ w_out,
                       unsigned short* __restrict__ xb,
                       unsigned short* __restrict__ wqkvT,
                       unsigned short* __restrict__ woutT,
                       float2* __restrict__ rope) {
    __shared__ unsigned short tile[64][65];
    int id = blockIdx.x, t = threadIdx.x;
    if (id < 1024) {
        int base = id * 256 + t;
#pragma unroll
        for (int k = 0; k < 4; ++k) {
            int i = base + k * 262144;
            float4 v = ((const float4*)x)[i];
            ushort4 o;
            o.x = f2bf(v.x); o.y = f2bf(v.y); o.z = f2bf(v.z); o.w = f2bf(v.w);
            ((ushort4*)xb)[i] = o;
        }
        return;
    }
    id -= 1024;
    if (id < 256) {
        int idx = id * 256 + t;                    // 65536 = 2048 s x 32 d
        int s = idx >> 5, d = idx & 31;
        float inv = __expf(-(float)d * 0.28782313662425572f);  // 10000^(-d/32)
        float sn, cs;
        sincosf((float)s * inv, &sn, &cs);
        rope[idx] = make_float2(cs, sn);
        return;
    }
    id -= 256;
    const float* src; unsigned short* dst; int N, kb, nb;
    if (id < 768) { src = w_qkv; dst = wqkvT; N = 3072; nb = (id % 48) * 64; kb = (id / 48) * 64; }
    else { id -= 768; src = w_out; dst = woutT; N = 1024; nb = (id % 16) * 64; kb = (id / 16) * 64; }
    const int K = 1024;
    for (int i = 0; i < 16; ++i) {
        int e = t + i * 256;
        int n_l = e & 63, k_l = e >> 6;
        tile[n_l][k_l] = f2bf(src[(size_t)(kb + k_l) * N + nb + n_l]);
    }
    __syncthreads();
    for (int i = 0; i < 16; ++i) {
        int e = t + i * 256;
        int k_l = e & 63, n_l = e >> 6;
        dst[(size_t)(nb + n_l) * K + kb + k_l] = tile[n_l][k_l];
    }
}

// ------------- QKV GEMM: 256x256 tile, BK=64, 8 waves, 4-phase counted pipeline -------------
// C = xb[4096][1024] @ wqkvT[3072][1024]^T.  Grid 12x16 (N,M); blocks region-pure:
// blockIdx.x 0-3 Q, 4-7 K (rope epilogue), 8-11 V (LDS-transpose epilogue).
// Schedule per K-tile kt (buf = kt&1):
//   P0: stage B(kt+1)lo -> nbuf | ds_read ks0 (A m0-7 + B n0-3) | MFMA n0-1 ks0 | bar
//   P1: stage B(kt+1)hi -> nbuf | ds_read ks1                   | MFMA n2-3 ks0 | bar
//   P2: stage A(kt+2)lo -> buf  (A reads of tile kt done at P1)  | MFMA n0-1 ks1 | bar
//   P3: stage A(kt+2)hi -> buf  | MFMA n2-3 ks1 | vmcnt(4) [tile kt+1 landed] | bar
// LDS XOR-swizzle (T2): LDS slot (row, c16) holds global k-slot c16^(row&7); achieved
// with pre-swizzled global source addrs (linear gload_lds dest) + swizzled ds_read.
__global__ __launch_bounds__(512, 2) void k_gemm_qkv(
    const unsigned short* __restrict__ A,
    const unsigned short* __restrict__ Bt,
    const float2* __restrict__ rope,
    unsigned short* __restrict__ Qg,
    unsigned short* __restrict__ Kg,
    unsigned short* __restrict__ Vt) {
    const int K = 1024;
    __shared__ __align__(16) union {
        struct { unsigned short Ab[2][256 * 64], Bb[2][256 * 64]; } g;  // 128 KB
        unsigned short vt[4][64][264];                                  // 132 KB V-transpose
    } sm;
    const int t = threadIdx.x;
    const int w = t >> 6, l = t & 63, quad = l >> 4, ln = l & 15;
    const int wr = w >> 2, wc = w & 3;            // wave grid 2M x 4N, 128x64 per wave
    const int mb = blockIdx.y * 256, nb = blockIdx.x * 256;
    const int lxr = l >> 3;                       // lane row within 8-row chunk
    const int swz = ((l & 7) ^ lxr) * 8;          // pre-swizzled src col (ushorts)

    v4f acc[8][4];
#pragma unroll
    for (int i = 0; i < 8; ++i)
#pragma unroll
        for (int j = 0; j < 4; ++j) acc[i][j] = (v4f){0.f, 0.f, 0.f, 0.f};

    // stage one 128x64 half-tile: 2 x gload_lds per wave (wave w covers rows [w*16, w*16+16))
    auto stageHT = [&](const unsigned short* src, int grow, int k0, unsigned short* lds) {
#pragma unroll
        for (int c = 0; c < 2; ++c) {
            int r0 = w * 16 + c * 8;
            gload_lds16(src + (size_t)(grow + r0 + lxr) * K + k0 + swz, lds + r0 * 64);
        }
    };
    // swizzled fragment read: row's k-slot g16 lives at LDS col slot g16^(row&7)
    auto frag = [&](const unsigned short* base, int row, int g16) -> v8s {
        return *(const v8s*)&base[row * 64 + ((g16 ^ (row & 7)) << 3)];
    };

    // prologue: tile0 complete + A1 halves (ledger: vmcnt(4) -> tile0 landed, A1 in flight)
    stageHT(A,  mb,       0,  &sm.g.Ab[0][0]);
    stageHT(A,  mb + 128, 0,  &sm.g.Ab[0][128 * 64]);
    stageHT(Bt, nb,       0,  &sm.g.Bb[0][0]);
    stageHT(Bt, nb + 128, 0,  &sm.g.Bb[0][128 * 64]);
    stageHT(A,  mb,       64, &sm.g.Ab[1][0]);
    stageHT(A,  mb + 128, 64, &sm.g.Ab[1][128 * 64]);
    VMWAIT(4);
    BAR();

    for (int kt = 0; kt < 16; ++kt) {
        const int buf = kt & 1, nbf = buf ^ 1;
        const unsigned short* Ap = &sm.g.Ab[buf][0];
        const unsigned short* Bp = &sm.g.Bb[buf][0];
        // ---- P0
        if (kt + 1 < 16) stageHT(Bt, nb, (kt + 1) * 64, &sm.g.Bb[nbf][0]);
        v8s a0[8], b0[4];
#pragma unroll
        for (int i = 0; i < 8; ++i) a0[i] = frag(Ap, wr * 128 + i * 16 + ln, quad);
#pragma unroll
        for (int j = 0; j < 4; ++j) b0[j] = frag(Bp, wc * 64 + j * 16 + ln, quad);
        __builtin_amdgcn_s_setprio(1);
#pragma unroll
        for (int i = 0; i < 8; ++i) {
            acc[i][0] = __builtin_amdgcn_mfma_f32_16x16x32_bf16(a0[i], b0[0], acc[i][0], 0, 0, 0);
            acc[i][1] = __builtin_amdgcn_mfma_f32_16x16x32_bf16(a0[i], b0[1], acc[i][1], 0, 0, 0);
        }
        __builtin_amdgcn_s_setprio(0);
        BAR();
        // ---- P1
        if (kt + 1 < 16) stageHT(Bt, nb + 128, (kt + 1) * 64, &sm.g.Bb[nbf][128 * 64]);
        v8s a1[8], b1[4];
#pragma unroll
        for (int i = 0; i < 8; ++i) a1[i] = frag(Ap, wr * 128 + i * 16 + ln, 4 + quad);
#pragma unroll
        for (int j = 0; j < 4; ++j) b1[j] = frag(Bp, wc * 64 + j * 16 + ln, 4 + quad);
        __builtin_amdgcn_s_setprio(1);
#pragma unroll
        for (int i = 0; i < 8; ++i) {
            acc[i][2] = __builtin_amdgcn_mfma_f32_16x16x32_bf16(a0[i], b0[2], acc[i][2], 0, 0, 0);
            acc[i][3] = __builtin_amdgcn_mfma_f32_16x16x32_bf16(a0[i], b0[3], acc[i][3], 0, 0, 0);
        }
        __builtin_amdgcn_s_setprio(0);
        BAR();
        // ---- P2 (all reads of tile kt done; buf regions re-stageable)
        if (kt + 2 < 16) stageHT(A, mb, (kt + 2) * 64, &sm.g.Ab[buf][0]);
        __builtin_amdgcn_s_setprio(1);
#pragma unroll
        for (int i = 0; i < 8; ++i) {
            acc[i][0] = __builtin_amdgcn_mfma_f32_16x16x32_bf16(a1[i], b1[0], acc[i][0], 0, 0, 0);
            acc[i][1] = __builtin_amdgcn_mfma_f32_16x16x32_bf16(a1[i], b1[1], acc[i][1], 0, 0, 0);
        }
        __builtin_amdgcn_s_setprio(0);
        BAR();
        // ---- P3
        if (kt + 2 < 16) stageHT(A, mb + 128, (kt + 2) * 64, &sm.g.Ab[buf][128 * 64]);
        __builtin_amdgcn_s_setprio(1);
#pragma unroll
        for (int i = 0; i < 8; ++i) {
            acc[i][2] = __builtin_amdgcn_mfma_f32_16x16x32_bf16(a1[i], b1[2], acc[i][2], 0, 0, 0);
            acc[i][3] = __builtin_amdgcn_mfma_f32_16x16x32_bf16(a1[i], b1[3], acc[i][3], 0, 0, 0);
        }
        __builtin_amdgcn_s_setprio(0);
        if (kt < 14)       VMWAIT(4);   // tile kt+1 fully landed; A(kt+2) stays in flight
        else if (kt == 14) VMWAIT(0);   // tail: tile 15 = A15(+B15) all landed
        if (kt < 15) BAR();
    }

    if (nb >= 2048) {                              // ---- V: LDS transpose epilogue
        __syncthreads();                           // all tile reads done; reuse LDS
#pragma unroll
        for (int i = 0; i < 8; ++i)
#pragma unroll
            for (int j = 0; j < 4; ++j) {
                int d = j * 16 + ln;
                int s0 = wr * 128 + i * 16 + quad * 4;
                ushort4 pk;
                pk.x = f2bf(acc[i][j][0]); pk.y = f2bf(acc[i][j][1]);
                pk.z = f2bf(acc[i][j][2]); pk.w = f2bf(acc[i][j][3]);
                *(ushort4*)&sm.vt[wc][d][s0] = pk;
            }
        __syncthreads();
        const int hbase = (nb & 1023) >> 6;
        const int b = mb >> 11, sbase = mb & 2047;
#pragma unroll
        for (int i = 0; i < 16; ++i) {
            int c = t + i * 512;                   // 8192 chunks of 16B
            int h2 = c >> 11, dd = (c >> 5) & 63, off = (c & 31) * 8;
            v8s val = *(const v8s*)&sm.vt[h2][dd][off];
            *(v8s*)(Vt + ((size_t)((b * 16 + hbase + h2) * 64 + dd) * 2048 + sbase + off)) = val;
        }
        return;
    }

    // ---- Q/K: rope epilogue via table (per wave: one head, cols nb + wc*64 .. +64)
    const int nbw = nb + wc * 64;
    const int region = nbw >> 10;                  // 0=Q, 1=K
    const int h = (nbw & 1023) >> 6;
    unsigned short* dst = region == 0 ? Qg : Kg;
    const float scale = region == 0 ? QSCALE : 1.0f;
#pragma unroll
    for (int jj = 0; jj < 2; ++jj) {
        const float2* rp = rope + jj * 16 + ln;
#pragma unroll
        for (int i = 0; i < 8; ++i)
#pragma unroll
            for (int r = 0; r < 4; ++r) {
                int row = mb + wr * 128 + i * 16 + quad * 4 + r;
                int s = row & 2047, b = row >> 11;
                float2 cs = rp[s * 32];
                float t1 = acc[i][jj][r], t2 = acc[i][jj + 2][r];
                size_t base = ((size_t)(b * 16 + h) * 2048 + s) * 64;
                dst[base + jj * 16 + ln]      = f2bf((t1 * cs.x - t2 * cs.y) * scale);
                dst[base + jj * 16 + ln + 32] = f2bf((t2 * cs.x + t1 * cs.y) * scale);
            }
    }
}

// ------------- output projection GEMM, 3-buffer counted-vmcnt pipeline, f32 out -------------
__global__ __launch_bounds__(256) void k_gemm_out(
    const unsigned short* __restrict__ A,      // Og [4096][1024]
    const unsigned short* __restrict__ Bt,     // woutT [1024][1024]
    float* __restrict__ C) {
    const int K = 1024, N = 1024;
    __shared__ __align__(16) unsigned short Ab[3][4096];
    __shared__ __align__(16) unsigned short Bb[3][4096];
    const int t = threadIdx.x;
    const int w = t >> 6, l = t & 63, quad = l >> 4, ln = l & 15;
    const int wm = (w >> 1) * 64, wn = (w & 1) * 64;
    const int mb = blockIdx.y * 128, nb = blockIdx.x * 128;

    v4f acc[4][4];
#pragma unroll
    for (int i = 0; i < 4; ++i)
#pragma unroll
        for (int j = 0; j < 4; ++j) acc[i][j] = (v4f){0.f, 0.f, 0.f, 0.f};

    auto stage = [&](int buf, int k0) {
#pragma unroll
        for (int u = 0; u < 2; ++u) {
            int e = t + u * 256;
            gload_lds16(A + (size_t)(mb + (e >> 2)) * K + k0 + (e & 3) * 8,
                        &Ab[buf][(w * 64 + u * 256) * 8]);
            gload_lds16(Bt + (size_t)(nb + (e >> 2)) * K + k0 + (e & 3) * 8,
                        &Bb[buf][(w * 64 + u * 256) * 8]);
        }
    };

    stage(0, 0);
    stage(1, 32);
    int cur = 0, nxt = 2;
    for (int itk = 0; itk < 32; ++itk) {
        if (itk < 31) PIPE_BARRIER_KEEP4();
        else          PIPE_BARRIER_DRAIN();
        if (itk + 2 < 32) {
            stage(nxt, (itk + 2) * 32);
            nxt = nxt == 2 ? 0 : nxt + 1;
        }
        v8s af[4], bfr[4];
#pragma unroll
        for (int i = 0; i < 4; ++i)
            af[i] = *(const v8s*)&Ab[cur][(wm + i * 16 + ln) * 32 + quad * 8];
#pragma unroll
        for (int j = 0; j < 4; ++j)
            bfr[j] = *(const v8s*)&Bb[cur][(wn + j * 16 + ln) * 32 + quad * 8];
#pragma unroll
        for (int i = 0; i < 4; ++i)
#pragma unroll
            for (int j = 0; j < 4; ++j)
                acc[i][j] = __builtin_amdgcn_mfma_f32_16x16x32_bf16(
                    af[i], bfr[j], acc[i][j], 0, 0, 0);
        cur = cur == 2 ? 0 : cur + 1;
    }

#pragma unroll
    for (int i = 0; i < 4; ++i) {
        int r0 = mb + wm + i * 16 + quad * 4;
#pragma unroll
        for (int j = 0; j < 4; ++j) {
            int c0 = nb + wn + j * 16 + ln;
#pragma unroll
            for (int r = 0; r < 4; ++r)
                C[(size_t)(r0 + r) * N + c0] = acc[i][j][r];
        }
    }
}

// ------------- causal flash attention, v8 (unchanged this round) -------------
__global__ __launch_bounds__(256) void k_flash(
    const unsigned short* __restrict__ Qg,   // [BH][S][64], scaled 0.125*log2e
    const unsigned short* __restrict__ Kg,   // [BH][S][64]
    const unsigned short* __restrict__ Vt,   // [BH][64][S]
    unsigned short* __restrict__ Og) {       // [B*S][1024]
    __shared__ __align__(16) unsigned short Kb[2][64 * 64];
    __shared__ __align__(16) unsigned short Vb[2][64 * 64];
    __shared__ __align__(16) unsigned short P[4][16][72];

    const int id = blockIdx.x;
    const int xcd = id & 7, slot = id >> 3;
    const int bh = xcd * 4 + (slot & 3);
    const int qt = 31 - (slot >> 2);                 // heavy tiles first
    const int qbase = qt * 64;
    const int nit = qt + 1;

    const int t = threadIdx.x, w = t >> 6, l = t & 63, quad = l >> 4, ln = l & 15;
    const int b = bh >> 4, h = bh & 15;

    const unsigned short* Qp = Qg + (size_t)bh * 2048 * 64;
    const unsigned short* Kp = Kg + (size_t)bh * 2048 * 64;
    const unsigned short* Vp = Vt + (size_t)bh * 64 * 2048;

    unsigned kst[2], vst[2];
    int cchunk = l & 7, rloc = l >> 3;
#pragma unroll
    for (int j = 0; j < 2; ++j) {
        int c = w + j * 4;
        int rr = c * 8 + rloc;
        int g = (cchunk + rr) & 7;
        kst[j] = (unsigned)(rr * 64 + g * 8);
        vst[j] = (unsigned)(rr * 2048 + g * 8);
    }
    const int c0 = ((quad - ln) & 7) * 8;
    const int c1 = ((quad + 4 - ln) & 7) * 8;
    const v8s ones = {0x3F80, 0x3F80, 0x3F80, 0x3F80, 0x3F80, 0x3F80, 0x3F80, 0x3F80};

    const int qrow = qbase + w * 16 + ln;
    v8s qf0 = *(const v8s*)(Qp + (size_t)qrow * 64 + quad * 8);
    v8s qf1 = *(const v8s*)(Qp + (size_t)qrow * 64 + quad * 8 + 32);

    v4f oacc[5];
#pragma unroll
    for (int dt = 0; dt < 5; ++dt) oacc[dt] = (v4f){0.f, 0.f, 0.f, 0.f};

    auto stage = [&](int buf, int kvb) {
        const unsigned short* kg = Kp + (size_t)kvb * 64;
        const unsigned short* vg = Vp + kvb;
#pragma unroll
        for (int j = 0; j < 2; ++j) {
            int c = w + j * 4;
            gload_lds16(kg + kst[j], &Kb[buf][c * 512]);
            gload_lds16(vg + vst[j], &Vb[buf][c * 512]);
        }
    };

    auto compute = [&](int buf, int it) {
        v4f sc[4];
#pragma unroll
        for (int kt = 0; kt < 4; ++kt) {
            int row = kt * 16 + ln;
            v8s k0 = *(const v8s*)&Kb[buf][row * 64 + c0];
            v8s k1 = *(const v8s*)&Kb[buf][row * 64 + c1];
            sc[kt] = (v4f){0.f, 0.f, 0.f, 0.f};
            sc[kt] = __builtin_amdgcn_mfma_f32_16x16x32_bf16(qf0, k0, sc[kt], 0, 0, 0);
            sc[kt] = __builtin_amdgcn_mfma_f32_16x16x32_bf16(qf1, k1, sc[kt], 0, 0, 0);
        }
        if (it == qt) {
            int q0 = qbase + w * 16 + quad * 4;
#pragma unroll
            for (int kt = 0; kt < 4; ++kt) {
                int kv = qbase + kt * 16 + ln;
#pragma unroll
                for (int r = 0; r < 4; ++r)
                    if (kv > q0 + r) sc[kt][r] = -1e30f;
            }
        }
#pragma unroll
        for (int kt = 0; kt < 4; ++kt)
#pragma unroll
            for (int r = 0; r < 4; ++r)
                sc[kt][r] = exp2f(sc[kt][r] - SOFTMAX_OFF);

#pragma unroll
        for (int kt = 0; kt < 4; ++kt) {
            union { __hip_bfloat162 hh; unsigned int u; } p01, p23;
            p01.hh = __float22bfloat162_rn(make_float2(sc[kt][0], sc[kt][1]));
            p23.hh = __float22bfloat162_rn(make_float2(sc[kt][2], sc[kt][3]));
            P[w][quad * 4 + 0][kt * 16 + ln] = (unsigned short)p01.u;
            P[w][quad * 4 + 1][kt * 16 + ln] = (unsigned short)(p01.u >> 16);
            P[w][quad * 4 + 2][kt * 16 + ln] = (unsigned short)p23.u;
            P[w][quad * 4 + 3][kt * 16 + ln] = (unsigned short)(p23.u >> 16);
        }
        LDS_FENCE();
        v8s pf0 = *(const v8s*)&P[w][ln][quad * 8];
        v8s pf1 = *(const v8s*)&P[w][ln][quad * 8 + 32];
        LDS_FENCE();
#pragma unroll
        for (int dt = 0; dt < 4; ++dt) {
            int row = dt * 16 + ln;
            v8s v0 = *(const v8s*)&Vb[buf][row * 64 + c0];
            v8s v1 = *(const v8s*)&Vb[buf][row * 64 + c1];
            oacc[dt] = __builtin_amdgcn_mfma_f32_16x16x32_bf16(pf0, v0, oacc[dt], 0, 0, 0);
            oacc[dt] = __builtin_amdgcn_mfma_f32_16x16x32_bf16(pf1, v1, oacc[dt], 0, 0, 0);
        }
        oacc[4] = __builtin_amdgcn_mfma_f32_16x16x32_bf16(pf0, ones, oacc[4], 0, 0, 0);
        oacc[4] = __builtin_amdgcn_mfma_f32_16x16x32_bf16(pf1, ones, oacc[4], 0, 0, 0);
    };

    stage(0, 0);
    int it = 0;
    for (;;) {
        __syncthreads();
        stage(1, (it + 1) * 64);
        compute(0, it);
        if (++it >= nit) break;
        __syncthreads();
        stage(0, (it + 1) * 64);
        compute(1, it);
        if (++it >= nit) break;
    }

    float rden[4];
#pragma unroll
    for (int r = 0; r < 4; ++r) rden[r] = 1.f / oacc[4][r];
#pragma unroll
    for (int dt = 0; dt < 4; ++dt)
#pragma unroll
        for (int r = 0; r < 4; ++r) {
            int s = qbase + w * 16 + quad * 4 + r;
            Og[(size_t)(b * 2048 + s) * 1024 + h * 64 + dt * 16 + ln] =
                f2bf(oacc[dt][r] * rden[r]);
        }
}

extern "C" void kernel_launch(void* const* d_in, const int* in_sizes, int n_in,
                              void* d_out, int out_size, void* d_ws, size_t ws_size,
                              hipStream_t stream) {
    const float* x     = (const float*)d_in[0];
    const float* w_qkv = (const float*)d_in[2];
    const float* w_out = (const float*)d_in[3];
    char* ws = (char*)d_ws;

    unsigned short* xb    = (unsigned short*)(ws);                      //  8 MB
    unsigned short* wqkvT = (unsigned short*)(ws + (size_t)(8 << 20));  //  6 MB
    unsigned short* woutT = (unsigned short*)(ws + (size_t)(14 << 20)); //  2 MB
    unsigned short* Qg    = (unsigned short*)(ws + (size_t)(16 << 20)); //  8 MB
    unsigned short* Kg    = (unsigned short*)(ws + (size_t)(24 << 20)); //  8 MB
    unsigned short* Vt    = (unsigned short*)(ws + (size_t)(32 << 20)); //  8 MB
    unsigned short* Og    = (unsigned short*)(ws + (size_t)(40 << 20)); //  8 MB
    float2*         rope  = (float2*)(ws + (size_t)(48 << 20));         // 512 KB

    k_prep<<<2304, 256, 0, stream>>>(x, w_qkv, w_out, xb, wqkvT, woutT, rope);
    k_gemm_qkv<<<dim3(12, 16), 512, 0, stream>>>(xb, wqkvT, rope, Qg, Kg, Vt);
    k_flash<<<1024, 256, 0, stream>>>(Qg, Kg, Vt, Og);
    k_gemm_out<<<dim3(8, 32), 256, 0, stream>>>(Og, woutT, (float*)d_out);
}

// Round 3
// 196.527 us; speedup vs baseline: 1.0134x; 1.0134x over previous
//
#include <hip/hip_runtime.h>
#include <hip/hip_bf16.h>
#include <stdint.h>

typedef float v4f __attribute__((ext_vector_type(4)));
typedef short v8s __attribute__((ext_vector_type(8)));

#define LOG2E 1.44269504088896f
#define QSCALE (0.125f * LOG2E)   // fold softmax log2-domain into Q pre-scale
#define SOFTMAX_OFF 16.0f         // fixed softmax offset (exact; cancels in O/l)

__device__ __forceinline__ unsigned short f2bf(float f) {
    unsigned int u = __float_as_uint(f);
    u += 0x7fffu + ((u >> 16) & 1u);          // RTNE
    return (unsigned short)(u >> 16);
}

// Compiler+HW LDS ordering fence for the intra-wave P exchange.
#define LDS_FENCE() __builtin_amdgcn_fence(__ATOMIC_ACQ_REL, "workgroup")

// async global->LDS, 16B per lane, LDS dest = wave-uniform base + lane*16
__device__ __forceinline__ void gload_lds16(const unsigned short* g, unsigned short* s) {
    __builtin_amdgcn_global_load_lds(
        (const __attribute__((address_space(1))) unsigned int*)g,
        (__attribute__((address_space(3))) unsigned int*)s, 16, 0, 0);
}

// barriers with memory clobber: loads may not be hoisted/sunk across
#define BAR()      asm volatile("s_barrier" ::: "memory")
#define VMWAIT(N)  asm volatile("s_waitcnt vmcnt(" #N ")" ::: "memory")

#define PIPE_BARRIER_KEEP4()                                   \
    do {                                                       \
        asm volatile("s_waitcnt vmcnt(4)" ::: "memory");       \
        __builtin_amdgcn_s_barrier();                          \
        asm volatile("" ::: "memory");                         \
    } while (0)
#define PIPE_BARRIER_DRAIN()                                   \
    do {                                                       \
        asm volatile("s_waitcnt vmcnt(0)" ::: "memory");       \
        __builtin_amdgcn_s_barrier();                          \
        asm volatile("" ::: "memory");                         \
    } while (0)

// ---------------- prep: cast + rope table + both weight transposes ----------------
__global__ void k_prep(const float* __restrict__ x,
                       const float* __restrict__ w_qkv,
                       const float* __restrict__ w_out,
                       unsigned short* __restrict__ xb,
                       unsigned short* __restrict__ wqkvT,
                       unsigned short* __restrict__ woutT,
                       float2* __restrict__ rope) {
    __shared__ unsigned short tile[64][65];
    int id = blockIdx.x, t = threadIdx.x;
    if (id < 1024) {
        int base = id * 256 + t;
#pragma unroll
        for (int k = 0; k < 4; ++k) {
            int i = base + k * 262144;
            float4 v = ((const float4*)x)[i];
            ushort4 o;
            o.x = f2bf(v.x); o.y = f2bf(v.y); o.z = f2bf(v.z); o.w = f2bf(v.w);
            ((ushort4*)xb)[i] = o;
        }
        return;
    }
    id -= 1024;
    if (id < 256) {
        int idx = id * 256 + t;                    // 65536 = 2048 s x 32 d
        int s = idx >> 5, d = idx & 31;
        float inv = __expf(-(float)d * 0.28782313662425572f);  // 10000^(-d/32)
        float sn, cs;
        sincosf((float)s * inv, &sn, &cs);
        rope[idx] = make_float2(cs, sn);
        return;
    }
    id -= 256;
    const float* src; unsigned short* dst; int N, kb, nb;
    if (id < 768) { src = w_qkv; dst = wqkvT; N = 3072; nb = (id % 48) * 64; kb = (id / 48) * 64; }
    else { id -= 768; src = w_out; dst = woutT; N = 1024; nb = (id % 16) * 64; kb = (id / 16) * 64; }
    const int K = 1024;
    for (int i = 0; i < 16; ++i) {
        int e = t + i * 256;
        int n_l = e & 63, k_l = e >> 6;
        tile[n_l][k_l] = f2bf(src[(size_t)(kb + k_l) * N + nb + n_l]);
    }
    __syncthreads();
    for (int i = 0; i < 16; ++i) {
        int e = t + i * 256;
        int k_l = e & 63, n_l = e >> 6;
        dst[(size_t)(nb + n_l) * K + kb + k_l] = tile[n_l][k_l];
    }
}

// ------------- QKV GEMM: 256x256 tile, BK=64, 8 waves, 4-phase counted pipeline -------------
// (unchanged from round 2: 52 us, bank-conflict-free via T2 swizzle)
__global__ __launch_bounds__(512, 2) void k_gemm_qkv(
    const unsigned short* __restrict__ A,
    const unsigned short* __restrict__ Bt,
    const float2* __restrict__ rope,
    unsigned short* __restrict__ Qg,
    unsigned short* __restrict__ Kg,
    unsigned short* __restrict__ Vt) {
    const int K = 1024;
    __shared__ __align__(16) union {
        struct { unsigned short Ab[2][256 * 64], Bb[2][256 * 64]; } g;  // 128 KB
        unsigned short vt[4][64][264];                                  // 132 KB V-transpose
    } sm;
    const int t = threadIdx.x;
    const int w = t >> 6, l = t & 63, quad = l >> 4, ln = l & 15;
    const int wr = w >> 2, wc = w & 3;            // wave grid 2M x 4N, 128x64 per wave
    const int mb = blockIdx.y * 256, nb = blockIdx.x * 256;
    const int lxr = l >> 3;                       // lane row within 8-row chunk
    const int swz = ((l & 7) ^ lxr) * 8;          // pre-swizzled src col (ushorts)

    v4f acc[8][4];
#pragma unroll
    for (int i = 0; i < 8; ++i)
#pragma unroll
        for (int j = 0; j < 4; ++j) acc[i][j] = (v4f){0.f, 0.f, 0.f, 0.f};

    auto stageHT = [&](const unsigned short* src, int grow, int k0, unsigned short* lds) {
#pragma unroll
        for (int c = 0; c < 2; ++c) {
            int r0 = w * 16 + c * 8;
            gload_lds16(src + (size_t)(grow + r0 + lxr) * K + k0 + swz, lds + r0 * 64);
        }
    };
    auto frag = [&](const unsigned short* base, int row, int g16) -> v8s {
        return *(const v8s*)&base[row * 64 + ((g16 ^ (row & 7)) << 3)];
    };

    stageHT(A,  mb,       0,  &sm.g.Ab[0][0]);
    stageHT(A,  mb + 128, 0,  &sm.g.Ab[0][128 * 64]);
    stageHT(Bt, nb,       0,  &sm.g.Bb[0][0]);
    stageHT(Bt, nb + 128, 0,  &sm.g.Bb[0][128 * 64]);
    stageHT(A,  mb,       64, &sm.g.Ab[1][0]);
    stageHT(A,  mb + 128, 64, &sm.g.Ab[1][128 * 64]);
    VMWAIT(4);
    BAR();

    for (int kt = 0; kt < 16; ++kt) {
        const int buf = kt & 1, nbf = buf ^ 1;
        const unsigned short* Ap = &sm.g.Ab[buf][0];
        const unsigned short* Bp = &sm.g.Bb[buf][0];
        // ---- P0
        if (kt + 1 < 16) stageHT(Bt, nb, (kt + 1) * 64, &sm.g.Bb[nbf][0]);
        v8s a0[8], b0[4];
#pragma unroll
        for (int i = 0; i < 8; ++i) a0[i] = frag(Ap, wr * 128 + i * 16 + ln, quad);
#pragma unroll
        for (int j = 0; j < 4; ++j) b0[j] = frag(Bp, wc * 64 + j * 16 + ln, quad);
        __builtin_amdgcn_s_setprio(1);
#pragma unroll
        for (int i = 0; i < 8; ++i) {
            acc[i][0] = __builtin_amdgcn_mfma_f32_16x16x32_bf16(a0[i], b0[0], acc[i][0], 0, 0, 0);
            acc[i][1] = __builtin_amdgcn_mfma_f32_16x16x32_bf16(a0[i], b0[1], acc[i][1], 0, 0, 0);
        }
        __builtin_amdgcn_s_setprio(0);
        BAR();
        // ---- P1
        if (kt + 1 < 16) stageHT(Bt, nb + 128, (kt + 1) * 64, &sm.g.Bb[nbf][128 * 64]);
        v8s a1[8], b1[4];
#pragma unroll
        for (int i = 0; i < 8; ++i) a1[i] = frag(Ap, wr * 128 + i * 16 + ln, 4 + quad);
#pragma unroll
        for (int j = 0; j < 4; ++j) b1[j] = frag(Bp, wc * 64 + j * 16 + ln, 4 + quad);
        __builtin_amdgcn_s_setprio(1);
#pragma unroll
        for (int i = 0; i < 8; ++i) {
            acc[i][2] = __builtin_amdgcn_mfma_f32_16x16x32_bf16(a0[i], b0[2], acc[i][2], 0, 0, 0);
            acc[i][3] = __builtin_amdgcn_mfma_f32_16x16x32_bf16(a0[i], b0[3], acc[i][3], 0, 0, 0);
        }
        __builtin_amdgcn_s_setprio(0);
        BAR();
        // ---- P2
        if (kt + 2 < 16) stageHT(A, mb, (kt + 2) * 64, &sm.g.Ab[buf][0]);
        __builtin_amdgcn_s_setprio(1);
#pragma unroll
        for (int i = 0; i < 8; ++i) {
            acc[i][0] = __builtin_amdgcn_mfma_f32_16x16x32_bf16(a1[i], b1[0], acc[i][0], 0, 0, 0);
            acc[i][1] = __builtin_amdgcn_mfma_f32_16x16x32_bf16(a1[i], b1[1], acc[i][1], 0, 0, 0);
        }
        __builtin_amdgcn_s_setprio(0);
        BAR();
        // ---- P3
        if (kt + 2 < 16) stageHT(A, mb + 128, (kt + 2) * 64, &sm.g.Ab[buf][128 * 64]);
        __builtin_amdgcn_s_setprio(1);
#pragma unroll
        for (int i = 0; i < 8; ++i) {
            acc[i][2] = __builtin_amdgcn_mfma_f32_16x16x32_bf16(a1[i], b1[2], acc[i][2], 0, 0, 0);
            acc[i][3] = __builtin_amdgcn_mfma_f32_16x16x32_bf16(a1[i], b1[3], acc[i][3], 0, 0, 0);
        }
        __builtin_amdgcn_s_setprio(0);
        if (kt < 14)       VMWAIT(4);
        else if (kt == 14) VMWAIT(0);
        if (kt < 15) BAR();
    }

    if (nb >= 2048) {                              // ---- V: LDS transpose epilogue
        __syncthreads();
#pragma unroll
        for (int i = 0; i < 8; ++i)
#pragma unroll
            for (int j = 0; j < 4; ++j) {
                int d = j * 16 + ln;
                int s0 = wr * 128 + i * 16 + quad * 4;
                ushort4 pk;
                pk.x = f2bf(acc[i][j][0]); pk.y = f2bf(acc[i][j][1]);
                pk.z = f2bf(acc[i][j][2]); pk.w = f2bf(acc[i][j][3]);
                *(ushort4*)&sm.vt[wc][d][s0] = pk;
            }
        __syncthreads();
        const int hbase = (nb & 1023) >> 6;
        const int b = mb >> 11, sbase = mb & 2047;
#pragma unroll
        for (int i = 0; i < 16; ++i) {
            int c = t + i * 512;                   // 8192 chunks of 16B
            int h2 = c >> 11, dd = (c >> 5) & 63, off = (c & 31) * 8;
            v8s val = *(const v8s*)&sm.vt[h2][dd][off];
            *(v8s*)(Vt + ((size_t)((b * 16 + hbase + h2) * 64 + dd) * 2048 + sbase + off)) = val;
        }
        return;
    }

    // ---- Q/K: rope epilogue via table (per wave: one head, cols nb + wc*64 .. +64)
    const int nbw = nb + wc * 64;
    const int region = nbw >> 10;                  // 0=Q, 1=K
    const int h = (nbw & 1023) >> 6;
    unsigned short* dst = region == 0 ? Qg : Kg;
    const float scale = region == 0 ? QSCALE : 1.0f;
#pragma unroll
    for (int jj = 0; jj < 2; ++jj) {
        const float2* rp = rope + jj * 16 + ln;
#pragma unroll
        for (int i = 0; i < 8; ++i)
#pragma unroll
            for (int r = 0; r < 4; ++r) {
                int row = mb + wr * 128 + i * 16 + quad * 4 + r;
                int s = row & 2047, b = row >> 11;
                float2 cs = rp[s * 32];
                float t1 = acc[i][jj][r], t2 = acc[i][jj + 2][r];
                size_t base = ((size_t)(b * 16 + h) * 2048 + s) * 64;
                dst[base + jj * 16 + ln]      = f2bf((t1 * cs.x - t2 * cs.y) * scale);
                dst[base + jj * 16 + ln + 32] = f2bf((t2 * cs.x + t1 * cs.y) * scale);
            }
    }
}

// ------------- output projection GEMM, 3-buffer counted-vmcnt pipeline, f32 out -------------
__global__ __launch_bounds__(256) void k_gemm_out(
    const unsigned short* __restrict__ A,      // Og [4096][1024]
    const unsigned short* __restrict__ Bt,     // woutT [1024][1024]
    float* __restrict__ C) {
    const int K = 1024, N = 1024;
    __shared__ __align__(16) unsigned short Ab[3][4096];
    __shared__ __align__(16) unsigned short Bb[3][4096];
    const int t = threadIdx.x;
    const int w = t >> 6, l = t & 63, quad = l >> 4, ln = l & 15;
    const int wm = (w >> 1) * 64, wn = (w & 1) * 64;
    const int mb = blockIdx.y * 128, nb = blockIdx.x * 128;

    v4f acc[4][4];
#pragma unroll
    for (int i = 0; i < 4; ++i)
#pragma unroll
        for (int j = 0; j < 4; ++j) acc[i][j] = (v4f){0.f, 0.f, 0.f, 0.f};

    auto stage = [&](int buf, int k0) {
#pragma unroll
        for (int u = 0; u < 2; ++u) {
            int e = t + u * 256;
            gload_lds16(A + (size_t)(mb + (e >> 2)) * K + k0 + (e & 3) * 8,
                        &Ab[buf][(w * 64 + u * 256) * 8]);
            gload_lds16(Bt + (size_t)(nb + (e >> 2)) * K + k0 + (e & 3) * 8,
                        &Bb[buf][(w * 64 + u * 256) * 8]);
        }
    };

    stage(0, 0);
    stage(1, 32);
    int cur = 0, nxt = 2;
    for (int itk = 0; itk < 32; ++itk) {
        if (itk < 31) PIPE_BARRIER_KEEP4();
        else          PIPE_BARRIER_DRAIN();
        if (itk + 2 < 32) {
            stage(nxt, (itk + 2) * 32);
            nxt = nxt == 2 ? 0 : nxt + 1;
        }
        v8s af[4], bfr[4];
#pragma unroll
        for (int i = 0; i < 4; ++i)
            af[i] = *(const v8s*)&Ab[cur][(wm + i * 16 + ln) * 32 + quad * 8];
#pragma unroll
        for (int j = 0; j < 4; ++j)
            bfr[j] = *(const v8s*)&Bb[cur][(wn + j * 16 + ln) * 32 + quad * 8];
#pragma unroll
        for (int i = 0; i < 4; ++i)
#pragma unroll
            for (int j = 0; j < 4; ++j)
                acc[i][j] = __builtin_amdgcn_mfma_f32_16x16x32_bf16(
                    af[i], bfr[j], acc[i][j], 0, 0, 0);
        cur = cur == 2 ? 0 : cur + 1;
    }

#pragma unroll
    for (int i = 0; i < 4; ++i) {
        int r0 = mb + wm + i * 16 + quad * 4;
#pragma unroll
        for (int j = 0; j < 4; ++j) {
            int c0 = nb + wn + j * 16 + ln;
#pragma unroll
            for (int r = 0; r < 4; ++r)
                C[(size_t)(r0 + r) * N + c0] = acc[i][j][r];
        }
    }
}

// ------------- causal flash attention, v9: counted-vmcnt barriers + setprio -------------
// Change vs v8: __syncthreads() (vmcnt(0)+lgkmcnt(0) drain per iter) replaced by
// counted pipeline: stage(next) issued first, then vmcnt(4) waits only for the
// CURRENT tile's 4 loads (oldest), barrier publishes across waves; end-of-iter
// barrier separates readers of buf^1 from next iter's overwrite. T5 setprio
// around MFMA clusters (attn +4-7%, m191).
__global__ __launch_bounds__(256) void k_flash(
    const unsigned short* __restrict__ Qg,   // [BH][S][64], scaled 0.125*log2e
    const unsigned short* __restrict__ Kg,   // [BH][S][64]
    const unsigned short* __restrict__ Vt,   // [BH][64][S]
    unsigned short* __restrict__ Og) {       // [B*S][1024]
    __shared__ __align__(16) unsigned short Kb[2][64 * 64];
    __shared__ __align__(16) unsigned short Vb[2][64 * 64];
    __shared__ __align__(16) unsigned short P[4][16][72];

    const int id = blockIdx.x;
    const int xcd = id & 7, slot = id >> 3;
    const int bh = xcd * 4 + (slot & 3);
    const int qt = 31 - (slot >> 2);                 // heavy tiles first
    const int qbase = qt * 64;
    const int nit = qt + 1;

    const int t = threadIdx.x, w = t >> 6, l = t & 63, quad = l >> 4, ln = l & 15;
    const int b = bh >> 4, h = bh & 15;

    const unsigned short* Qp = Qg + (size_t)bh * 2048 * 64;
    const unsigned short* Kp = Kg + (size_t)bh * 2048 * 64;
    const unsigned short* Vp = Vt + (size_t)bh * 64 * 2048;

    unsigned kst[2], vst[2];
    int cchunk = l & 7, rloc = l >> 3;
#pragma unroll
    for (int j = 0; j < 2; ++j) {
        int c = w + j * 4;
        int rr = c * 8 + rloc;
        int g = (cchunk + rr) & 7;
        kst[j] = (unsigned)(rr * 64 + g * 8);
        vst[j] = (unsigned)(rr * 2048 + g * 8);
    }
    const int c0 = ((quad - ln) & 7) * 8;
    const int c1 = ((quad + 4 - ln) & 7) * 8;
    const v8s ones = {0x3F80, 0x3F80, 0x3F80, 0x3F80, 0x3F80, 0x3F80, 0x3F80, 0x3F80};

    const int qrow = qbase + w * 16 + ln;
    v8s qf0 = *(const v8s*)(Qp + (size_t)qrow * 64 + quad * 8);
    v8s qf1 = *(const v8s*)(Qp + (size_t)qrow * 64 + quad * 8 + 32);

    v4f oacc[5];
#pragma unroll
    for (int dt = 0; dt < 5; ++dt) oacc[dt] = (v4f){0.f, 0.f, 0.f, 0.f};

    auto stage = [&](int buf, int kvb) {
        const unsigned short* kg = Kp + (size_t)kvb * 64;
        const unsigned short* vg = Vp + kvb;
#pragma unroll
        for (int j = 0; j < 2; ++j) {
            int c = w + j * 4;
            gload_lds16(kg + kst[j], &Kb[buf][c * 512]);
            gload_lds16(vg + vst[j], &Vb[buf][c * 512]);
        }
    };

    auto compute = [&](int buf, int it) {
        v4f sc[4];
#pragma unroll
        for (int kt = 0; kt < 4; ++kt) {
            int row = kt * 16 + ln;
            v8s k0 = *(const v8s*)&Kb[buf][row * 64 + c0];
            v8s k1 = *(const v8s*)&Kb[buf][row * 64 + c1];
            sc[kt] = (v4f){0.f, 0.f, 0.f, 0.f};
            sc[kt] = __builtin_amdgcn_mfma_f32_16x16x32_bf16(qf0, k0, sc[kt], 0, 0, 0);
            sc[kt] = __builtin_amdgcn_mfma_f32_16x16x32_bf16(qf1, k1, sc[kt], 0, 0, 0);
        }
        if (it == qt) {
            int q0 = qbase + w * 16 + quad * 4;
#pragma unroll
            for (int kt = 0; kt < 4; ++kt) {
                int kv = qbase + kt * 16 + ln;
#pragma unroll
                for (int r = 0; r < 4; ++r)
                    if (kv > q0 + r) sc[kt][r] = -1e30f;
            }
        }
#pragma unroll
        for (int kt = 0; kt < 4; ++kt)
#pragma unroll
            for (int r = 0; r < 4; ++r)
                sc[kt][r] = exp2f(sc[kt][r] - SOFTMAX_OFF);

#pragma unroll
        for (int kt = 0; kt < 4; ++kt) {
            union { __hip_bfloat162 hh; unsigned int u; } p01, p23;
            p01.hh = __float22bfloat162_rn(make_float2(sc[kt][0], sc[kt][1]));
            p23.hh = __float22bfloat162_rn(make_float2(sc[kt][2], sc[kt][3]));
            P[w][quad * 4 + 0][kt * 16 + ln] = (unsigned short)p01.u;
            P[w][quad * 4 + 1][kt * 16 + ln] = (unsigned short)(p01.u >> 16);
            P[w][quad * 4 + 2][kt * 16 + ln] = (unsigned short)p23.u;
            P[w][quad * 4 + 3][kt * 16 + ln] = (unsigned short)(p23.u >> 16);
        }
        LDS_FENCE();
        v8s pf0 = *(const v8s*)&P[w][ln][quad * 8];
        v8s pf1 = *(const v8s*)&P[w][ln][quad * 8 + 32];
        LDS_FENCE();
        __builtin_amdgcn_s_setprio(1);
#pragma unroll
        for (int dt = 0; dt < 4; ++dt) {
            int row = dt * 16 + ln;
            v8s v0 = *(const v8s*)&Vb[buf][row * 64 + c0];
            v8s v1 = *(const v8s*)&Vb[buf][row * 64 + c1];
            oacc[dt] = __builtin_amdgcn_mfma_f32_16x16x32_bf16(pf0, v0, oacc[dt], 0, 0, 0);
            oacc[dt] = __builtin_amdgcn_mfma_f32_16x16x32_bf16(pf1, v1, oacc[dt], 0, 0, 0);
        }
        oacc[4] = __builtin_amdgcn_mfma_f32_16x16x32_bf16(pf0, ones, oacc[4], 0, 0, 0);
        oacc[4] = __builtin_amdgcn_mfma_f32_16x16x32_bf16(pf1, ones, oacc[4], 0, 0, 0);
        __builtin_amdgcn_s_setprio(0);
    };

    // pipeline: stage(next) in flight across the counted barrier; vmcnt(4)
    // proves THIS tile's 4 loads landed (per-wave), BAR publishes collectively.
    stage(0, 0);
    for (int it = 0;;) {
        const int buf = it & 1;
        stage(buf ^ 1, (it + 1) * 64);   // prefetch next tile (over-reads are in-workspace)
        VMWAIT(4);                       // wait own stage(buf); stage(buf^1) stays in flight
        BAR();                           // all waves' stage(buf) landed
        compute(buf, it);
        if (++it >= nit) break;
        BAR();                           // readers of buf^1 done before it is overwritten
    }

    float rden[4];
#pragma unroll
    for (int r = 0; r < 4; ++r) rden[r] = 1.f / oacc[4][r];
#pragma unroll
    for (int dt = 0; dt < 4; ++dt)
#pragma unroll
        for (int r = 0; r < 4; ++r) {
            int s = qbase + w * 16 + quad * 4 + r;
            Og[(size_t)(b * 2048 + s) * 1024 + h * 64 + dt * 16 + ln] =
                f2bf(oacc[dt][r] * rden[r]);
        }
}

extern "C" void kernel_launch(void* const* d_in, const int* in_sizes, int n_in,
                              void* d_out, int out_size, void* d_ws, size_t ws_size,
                              hipStream_t stream) {
    const float* x     = (const float*)d_in[0];
    const float* w_qkv = (const float*)d_in[2];
    const float* w_out = (const float*)d_in[3];
    char* ws = (char*)d_ws;

    unsigned short* xb    = (unsigned short*)(ws);                      //  8 MB
    unsigned short* wqkvT = (unsigned short*)(ws + (size_t)(8 << 20));  //  6 MB
    unsigned short* woutT = (unsigned short*)(ws + (size_t)(14 << 20)); //  2 MB
    unsigned short* Qg    = (unsigned short*)(ws + (size_t)(16 << 20)); //  8 MB
    unsigned short* Kg    = (unsigned short*)(ws + (size_t)(24 << 20)); //  8 MB (flash K over-prefetch -> Vt, read-only)
    unsigned short* Vt    = (unsigned short*)(ws + (size_t)(32 << 20)); //  8 MB (flash V over-prefetch -> Og, read-only)
    unsigned short* Og    = (unsigned short*)(ws + (size_t)(40 << 20)); //  8 MB
    float2*         rope  = (float2*)(ws + (size_t)(48 << 20));         // 512 KB

    k_prep<<<2304, 256, 0, stream>>>(x, w_qkv, w_out, xb, wqkvT, woutT, rope);
    k_gemm_qkv<<<dim3(12, 16), 512, 0, stream>>>(xb, wqkvT, rope, Qg, Kg, Vt);
    k_flash<<<1024, 256, 0, stream>>>(Qg, Kg, Vt, Og);
    k_gemm_out<<<dim3(8, 32), 256, 0, stream>>>(Og, woutT, (float*)d_out);
}